// Round 8
// baseline (19517.332 us; speedup 1.0000x reference)
//
#include <hip/hip_runtime.h>

#define N_EXC  512
#define NTOT   640
#define NIN    16
#define BATCH  64
#define TSTEPS 1000
#define CHUNK  160      // units per block
#define NBLKG  4        // blocks per batch sample
#define THREADS 1024
#define NPT    10       // n per thread (16 ti-groups * 10 = 160)
#define KPT    10       // k per thread (64 tj-groups * 10 = 640)
// ALPHA = 0.5, NOISE_SCALE = 0.01

typedef float f32x4 __attribute__((ext_vector_type(4)));
typedef float f32x2 __attribute__((ext_vector_type(2)));

// ---------------------------------------------------------------------------
// JAX threefry2x32, key = jax.random.key(42) -> (0, 42); partitionable bits
// ---------------------------------------------------------------------------
__device__ __forceinline__ void threefry_0_42(unsigned x0, unsigned x1,
                                              unsigned& o0, unsigned& o1) {
    const unsigned ks1 = 42u;
    const unsigned ks2 = 0x1BD11BDAu ^ 42u;
    x0 += 0u; x1 += ks1;
#define TF_RND(r) { x0 += x1; x1 = (x1 << (r)) | (x1 >> (32 - (r))); x1 ^= x0; }
    TF_RND(13) TF_RND(15) TF_RND(26) TF_RND(6)
    x0 += ks1; x1 += ks2 + 1u;
    TF_RND(17) TF_RND(29) TF_RND(16) TF_RND(24)
    x0 += ks2; x1 += 0u + 2u;
    TF_RND(13) TF_RND(15) TF_RND(26) TF_RND(6)
    x0 += 0u; x1 += ks1 + 3u;
    TF_RND(17) TF_RND(29) TF_RND(16) TF_RND(24)
    x0 += ks1; x1 += ks2 + 4u;
    TF_RND(13) TF_RND(15) TF_RND(26) TF_RND(6)
    x0 += ks2; x1 += 0u + 5u;
#undef TF_RND
    o0 = x0; o1 = x1;
}

__device__ __forceinline__ unsigned jax_bits_partitionable(unsigned idx) {
    unsigned o0, o1;
    threefry_0_42(0u, idx, o0, o1);
    return o0 ^ o1;
}

// bits -> jax.random.normal sample scaled by NOISE_SCALE*sqrt(ALPHA), f32-exact
__device__ __forceinline__ float noise_from_bits(unsigned bits) {
    float f = __uint_as_float(0x3f800000u | (bits >> 9)) - 1.0f;   // [0,1)
    float u = __fadd_rn(__fmul_rn(f, 2.0f), -0.99999994f);
    u = fmaxf(-0.99999994f, u);
    float w = -log1pf(-__fmul_rn(u, u));
    float p;
    if (w < 5.0f) {
        float ww = w - 2.5f;
        p = 2.81022636e-08f;
        p = fmaf(p, ww, 3.43273939e-07f);
        p = fmaf(p, ww, -3.5233877e-06f);
        p = fmaf(p, ww, -4.39150654e-06f);
        p = fmaf(p, ww, 0.00021858087f);
        p = fmaf(p, ww, -0.00125372503f);
        p = fmaf(p, ww, -0.00417768164f);
        p = fmaf(p, ww, 0.246640727f);
        p = fmaf(p, ww, 1.50140941f);
    } else {
        float ww = sqrtf(w) - 3.0f;
        p = -0.000200214257f;
        p = fmaf(p, ww, 0.000100950558f);
        p = fmaf(p, ww, 0.00134934322f);
        p = fmaf(p, ww, -0.00367342844f);
        p = fmaf(p, ww, 0.00573950773f);
        p = fmaf(p, ww, -0.0076224613f);
        p = fmaf(p, ww, 0.00943887047f);
        p = fmaf(p, ww, 1.00167406f);
        p = fmaf(p, ww, 2.83297682f);
    }
    float z = 1.41421354f * (p * u);
    return (0.01f * 0.70710677f) * z;
}

#define FOR10(M) M(0) M(1) M(2) M(3) M(4) M(5) M(6) M(7) M(8) M(9)

// ---------------------------------------------------------------------------
// Persistent kernel: 256 blocks = 4 chunk-blocks x 64 batches, 1024 threads.
// 100 weights/thread (10n x 10k) fits the allocator's 128-VGPR target
// (rounds 4-7: every 512-thread/200-weight variant spilled at a stubborn
// 128-VGPR cap regardless of launch_bounds / waves_per_eu hints).
// 16 waves/CU = 4 waves/EU, 1 block/CU, 256 blocks co-resident.
// ---------------------------------------------------------------------------
__global__ __attribute__((amdgpu_flat_work_group_size(THREADS, THREADS),
                          amdgpu_waves_per_eu(4, 4)))
void eirnn_sync(const float* __restrict__ inputs, const float* __restrict__ Wraw,
                const float* __restrict__ W_in, const float* __restrict__ W_out,
                const float* __restrict__ b_out, float* __restrict__ rates_out,
                float* __restrict__ outs_out, unsigned* __restrict__ flags,
                float* __restrict__ rbuf) {
    const int b   = blockIdx.x & 63;
    const int g   = blockIdx.x >> 6;
    const int tid = threadIdx.x;
    const int ti  = tid & 15;        // n-group (0..15)
    const int tj  = tid >> 4;        // k-group (0..63)
    const int wv  = tid >> 6;        // wave (0..15)
    const int nbase = g * CHUNK;
    const int nloc  = nbase + ti * NPT;   // first owned n (global id)
    const int kbase = tj * KPT;           // first owned k

    __shared__ __align__(16) float r_all[NTOT];
    __shared__ __align__(8) float part[16 * CHUNK];     // [wave][160]
    __shared__ float win_s[CHUNK * 17];
    __shared__ float u_s[NIN];
    __shared__ float red0[8], red1[8];

    // ---- named weight registers: 10 k-slots x (f32x4,f32x4,f32x2) over n ----
#define DECLW(K) f32x4 wA##K, wB##K; f32x2 wC##K;
    FOR10(DECLW)
#undef DECLW

    // ---- one-time: load weight panel (dale applied on the fly) ----
#define LOADW(K) {                                                          \
        const int k_ = kbase + (K);                                         \
        const float sg_ = (k_ < N_EXC) ? 1.0f : -1.0f;                      \
        const float* c_ = Wraw + (size_t)nloc * NTOT + k_;                  \
        float v0 = fabsf(c_[0 * NTOT]) * sg_; if (k_ == nloc + 0) v0 = 0.f; \
        float v1 = fabsf(c_[1 * NTOT]) * sg_; if (k_ == nloc + 1) v1 = 0.f; \
        float v2 = fabsf(c_[2 * NTOT]) * sg_; if (k_ == nloc + 2) v2 = 0.f; \
        float v3 = fabsf(c_[3 * NTOT]) * sg_; if (k_ == nloc + 3) v3 = 0.f; \
        float v4 = fabsf(c_[4 * NTOT]) * sg_; if (k_ == nloc + 4) v4 = 0.f; \
        float v5 = fabsf(c_[5 * NTOT]) * sg_; if (k_ == nloc + 5) v5 = 0.f; \
        float v6 = fabsf(c_[6 * NTOT]) * sg_; if (k_ == nloc + 6) v6 = 0.f; \
        float v7 = fabsf(c_[7 * NTOT]) * sg_; if (k_ == nloc + 7) v7 = 0.f; \
        float v8 = fabsf(c_[8 * NTOT]) * sg_; if (k_ == nloc + 8) v8 = 0.f; \
        float v9 = fabsf(c_[9 * NTOT]) * sg_; if (k_ == nloc + 9) v9 = 0.f; \
        wA##K = (f32x4){v0, v1, v2, v3};                                    \
        wB##K = (f32x4){v4, v5, v6, v7};                                    \
        wC##K = (f32x2){v8, v9};                                            \
    }
    FOR10(LOADW)
#undef LOADW

    // W_in chunk -> LDS (padded stride 17)
    for (int i = tid; i < CHUNK * NIN; i += THREADS) {
        int o = i >> 4, j = i & 15;
        win_s[o * 17 + j] = W_in[(nbase + o) * NIN + j];
    }
    // readout weights: block g==0, threads 0..511 cover exactly r[:512]
    float wo0 = 0.0f, wo1 = 0.0f;
    if (g == 0 && tid < N_EXC) { wo0 = W_out[tid]; wo1 = W_out[N_EXC + tid]; }
    const float bo0 = b_out[0], bo1 = b_out[1];

    const float* inp_b = inputs    + (size_t)b * TSTEPS * NIN;
    float* rates_b     = rates_out + (size_t)b * TSTEPS * NTOT;
    float* outs_b      = outs_out  + (size_t)b * TSTEPS * 2;
    unsigned* myflag   = flags + (b * NBLKG + g);

    float x = 0.0f;   // owner state for tid < CHUNK
    __syncthreads();  // win_s ready

    for (int t = 0; t < TSTEPS; ++t) {
        // ---- phase A: rates from current x; publish own chunk -------------
        if (tid < CHUNK) {
            float r = fmaxf(x, 0.0f) + log1pf(expf(-fabsf(x)));
            r_all[nbase + tid] = r;
            rates_b[t * NTOT + nbase + tid] = r;
            float* dst = rbuf + ((size_t)((t & 1) * BATCH + b) * NBLKG + g) * CHUNK + tid;
            __hip_atomic_store(dst, r, __ATOMIC_RELAXED, __HIP_MEMORY_SCOPE_AGENT);
        } else if (tid < CHUNK + NIN) {
            u_s[tid - CHUNK] = inp_b[t * NIN + (tid - CHUNK)];
        }
        __syncthreads();   // drains owners' rbuf stores before flag

        if (tid == 0)
            __hip_atomic_store(myflag, (unsigned)(t + 1), __ATOMIC_RELEASE,
                               __HIP_MEMORY_SCOPE_AGENT);
        if (tid >= 1 && tid < NBLKG) {          // 3 pollers
            int p = tid - 1;
            int gg = p + (p >= g ? 1 : 0);
            unsigned* f = flags + b * NBLKG + gg;
            while (__hip_atomic_load(f, __ATOMIC_ACQUIRE, __HIP_MEMORY_SCOPE_AGENT)
                   < (unsigned)(t + 1)) {
                __builtin_amdgcn_s_sleep(1);
            }
        }
        __syncthreads();

        // ---- phase B: pull remote chunks into r_all ------------------------
        if (tid < 3 * CHUNK) {
            int p = tid / CHUNK;
            int gg = p + (p >= g ? 1 : 0);
            int o = tid - p * CHUNK;
            const float* src = rbuf + ((size_t)((t & 1) * BATCH + b) * NBLKG + gg) * CHUNK + o;
            r_all[gg * CHUNK + o] =
                __hip_atomic_load(src, __ATOMIC_RELAXED, __HIP_MEMORY_SCOPE_AGENT);
        }
        __syncthreads();

        // ---- phase C: register-resident GEMV + in-wave k-reduction ---------
        {
            f32x4 accA = {0.f, 0.f, 0.f, 0.f};
            f32x4 accB = {0.f, 0.f, 0.f, 0.f};
            f32x2 accC = {0.f, 0.f};
#define FMAK(K) { float rk_ = r_all[kbase + (K)];                           \
                  accA += wA##K * rk_; accB += wB##K * rk_;                 \
                  accC += wC##K * rk_; }
            FOR10(FMAK)
#undef FMAK
            // reduce over the 4 tj-groups inside this wave (lane bits 4,5)
            float s0 = accA.x, s1 = accA.y, s2 = accA.z, s3 = accA.w;
            float s4 = accB.x, s5 = accB.y, s6 = accB.z, s7 = accB.w;
            float s8 = accC.x, s9 = accC.y;
#define WRED(S) { S += __shfl_xor(S, 16); S += __shfl_xor(S, 32); }
            WRED(s0) WRED(s1) WRED(s2) WRED(s3) WRED(s4)
            WRED(s5) WRED(s6) WRED(s7) WRED(s8) WRED(s9)
#undef WRED
            if ((tid & 63) < 16) {              // lane == ti
                float* pp = &part[wv * CHUNK + ti * NPT];
                ((f32x2*)pp)[0] = (f32x2){s0, s1};
                ((f32x2*)pp)[1] = (f32x2){s2, s3};
                ((f32x2*)pp)[2] = (f32x2){s4, s5};
                ((f32x2*)pp)[3] = (f32x2){s6, s7};
                ((f32x2*)pp)[4] = (f32x2){s8, s9};
            }
        }

        // readout partials on g==0 (r_all is complete r_t); threads 0..511
        if (g == 0 && tid < N_EXC) {
            float rr = r_all[tid];
            float p0 = rr * wo0, p1 = rr * wo1;
#pragma unroll
            for (int off = 32; off; off >>= 1) {
                p0 += __shfl_down(p0, off);
                p1 += __shfl_down(p1, off);
            }
            if ((tid & 63) == 0) { red0[wv] = p0; red1[wv] = p1; }
        }
        __syncthreads();

        // ---- phase D: owner state update ----------------------------------
        if (tid < CHUNK) {
            float rec = 0.0f;
#pragma unroll
            for (int j = 0; j < 16; ++j) rec += part[j * CHUNK + tid];
            float ext = 0.0f;
#pragma unroll
            for (int j = 0; j < NIN; ++j)
                ext = fmaf(win_s[tid * 17 + j], u_s[j], ext);
            unsigned idx = (unsigned)(t * (BATCH * NTOT) + b * NTOT + (nbase + tid));
            float eps = noise_from_bits(jax_bits_partitionable(idx));
            x = (0.5f * x + 0.5f * (rec + ext)) + eps;
        }
        if (g == 0 && tid == 0) {
            float y0 = bo0, y1 = bo1;
#pragma unroll
            for (int k = 0; k < 8; ++k) { y0 += red0[k]; y1 += red1[k]; }
            outs_b[t * 2 + 0] = y0;
            outs_b[t * 2 + 1] = y1;
        }
        __syncthreads();   // protect r_all/part/u_s/red before next iteration
    }
}

// ---------------------------------------------------------------------------
extern "C" void kernel_launch(void* const* d_in, const int* in_sizes, int n_in,
                              void* d_out, int out_size, void* d_ws, size_t ws_size,
                              hipStream_t stream) {
    const float* inputs = (const float*)d_in[0];   // [64,1000,16]
    const float* Wraw   = (const float*)d_in[1];   // [640,640]
    const float* W_in   = (const float*)d_in[2];   // [640,16]
    const float* W_out  = (const float*)d_in[3];   // [2,512]
    const float* b_out  = (const float*)d_in[4];   // [2]

    float* out   = (float*)d_out;
    float* rates = out;                                    // [64,1000,640]
    float* outs  = out + (size_t)BATCH * TSTEPS * NTOT;    // [64,1000,2]

    unsigned* flags = (unsigned*)d_ws;                     // 64*4 u32, zeroed
    float* rbuf = (float*)((char*)d_ws + 4096);            // [2][64][4][160] f32

    hipMemsetAsync(d_ws, 0, 4096, stream);
    eirnn_sync<<<dim3(NBLKG * BATCH), dim3(THREADS), 0, stream>>>(
        inputs, Wraw, W_in, W_out, b_out, rates, outs, flags, rbuf);
}

// Round 10
// 11557.441 us; speedup vs baseline: 1.6887x; 1.6887x over previous
//
#include <hip/hip_runtime.h>

#define N_EXC  512
#define NTOT   640
#define NIN    16
#define BATCH  64
#define TSTEPS 1000
#define CHUNK  160      // units per block
#define NBLKG  4        // blocks per batch sample
#define THREADS 512
#define NPT    10       // n per thread (16 ti-groups * 10 = 160)
#define KPT    20       // k per thread (32 tj-groups * 20 = 640)
// ALPHA = 0.5, NOISE_SCALE = 0.01

typedef float    f32x2 __attribute__((ext_vector_type(2)));
typedef unsigned u32x4 __attribute__((ext_vector_type(4)));
typedef unsigned u32x2 __attribute__((ext_vector_type(2)));

// ---------------------------------------------------------------------------
// JAX threefry2x32, key = jax.random.key(42) -> (0, 42); partitionable bits
// ---------------------------------------------------------------------------
__device__ __forceinline__ void threefry_0_42(unsigned x0, unsigned x1,
                                              unsigned& o0, unsigned& o1) {
    const unsigned ks1 = 42u;
    const unsigned ks2 = 0x1BD11BDAu ^ 42u;
    x0 += 0u; x1 += ks1;
#define TF_RND(r) { x0 += x1; x1 = (x1 << (r)) | (x1 >> (32 - (r))); x1 ^= x0; }
    TF_RND(13) TF_RND(15) TF_RND(26) TF_RND(6)
    x0 += ks1; x1 += ks2 + 1u;
    TF_RND(17) TF_RND(29) TF_RND(16) TF_RND(24)
    x0 += ks2; x1 += 0u + 2u;
    TF_RND(13) TF_RND(15) TF_RND(26) TF_RND(6)
    x0 += 0u; x1 += ks1 + 3u;
    TF_RND(17) TF_RND(29) TF_RND(16) TF_RND(24)
    x0 += ks1; x1 += ks2 + 4u;
    TF_RND(13) TF_RND(15) TF_RND(26) TF_RND(6)
    x0 += ks2; x1 += 0u + 5u;
#undef TF_RND
    o0 = x0; o1 = x1;
}

__device__ __forceinline__ unsigned jax_bits_partitionable(unsigned idx) {
    unsigned o0, o1;
    threefry_0_42(0u, idx, o0, o1);
    return o0 ^ o1;
}

// bits -> jax.random.normal sample scaled by NOISE_SCALE*sqrt(ALPHA), f32-exact
__device__ __forceinline__ float noise_from_bits(unsigned bits) {
    float f = __uint_as_float(0x3f800000u | (bits >> 9)) - 1.0f;   // [0,1)
    float u = __fadd_rn(__fmul_rn(f, 2.0f), -0.99999994f);
    u = fmaxf(-0.99999994f, u);
    float w = -log1pf(-__fmul_rn(u, u));
    float p;
    if (w < 5.0f) {
        float ww = w - 2.5f;
        p = 2.81022636e-08f;
        p = fmaf(p, ww, 3.43273939e-07f);
        p = fmaf(p, ww, -3.5233877e-06f);
        p = fmaf(p, ww, -4.39150654e-06f);
        p = fmaf(p, ww, 0.00021858087f);
        p = fmaf(p, ww, -0.00125372503f);
        p = fmaf(p, ww, -0.00417768164f);
        p = fmaf(p, ww, 0.246640727f);
        p = fmaf(p, ww, 1.50140941f);
    } else {
        float ww = sqrtf(w) - 3.0f;
        p = -0.000200214257f;
        p = fmaf(p, ww, 0.000100950558f);
        p = fmaf(p, ww, 0.00134934322f);
        p = fmaf(p, ww, -0.00367342844f);
        p = fmaf(p, ww, 0.00573950773f);
        p = fmaf(p, ww, -0.0076224613f);
        p = fmaf(p, ww, 0.00943887047f);
        p = fmaf(p, ww, 1.00167406f);
        p = fmaf(p, ww, 2.83297682f);
    }
    float z = 1.41421354f * (p * u);
    return (0.01f * 0.70710677f) * z;
}

// round-to-nearest-even bf16 (low 16 bits of result)
__device__ __forceinline__ unsigned rne_bf16(float f) {
    unsigned u = __float_as_uint(f);
    return (u + 0x7FFFu + ((u >> 16) & 1u)) >> 16;
}

// dale-transformed weights for units (n0,n1) at input k, bf16-packed lo|hi<<16
__device__ __forceinline__ unsigned packw2(const float* __restrict__ W,
                                           int n0, int n1, int k, float sg) {
    float lo = fabsf(W[(size_t)n0 * NTOT + k]) * sg; if (n0 == k) lo = 0.f;
    float hi = fabsf(W[(size_t)n1 * NTOT + k]) * sg; if (n1 == k) hi = 0.f;
    return rne_bf16(lo) | (rne_bf16(hi) << 16);
}

// packed u32 -> f32x2 (bf16 lo/hi widened exactly)
__device__ __forceinline__ f32x2 uf2(unsigned u) {
    u32x2 t = {u << 16, u & 0xFFFF0000u};
    return __builtin_bit_cast(f32x2, t);
}

#define FOR20(M) M(0) M(1) M(2) M(3) M(4) M(5) M(6) M(7) M(8) M(9) \
                 M(10) M(11) M(12) M(13) M(14) M(15) M(16) M(17) M(18) M(19)

// ---------------------------------------------------------------------------
// Persistent kernel: 256 blocks = 4 chunk-blocks x 64 batches, 512 threads.
// PROVEN topology (r4-r8): 1 block/CU co-residency holds for ANY VGPR<=256 —
// an allocator surprise can only spill, never deadlock (r9 lesson: 2-blocks/CU
// co-residency deadlocked when VGPR exceeded 128).
// Weights bf16-packed into 100 NAMED u32 regs/thread (20 k x 5 n-pairs);
// demand ~125 fits the allocator's observed 128-VGPR preference.
// ---------------------------------------------------------------------------
__global__ __attribute__((amdgpu_waves_per_eu(2, 2))) __launch_bounds__(THREADS)
void eirnn_sync(const float* __restrict__ inputs, const float* __restrict__ Wraw,
                const float* __restrict__ W_in, const float* __restrict__ W_out,
                const float* __restrict__ b_out, float* __restrict__ rates_out,
                float* __restrict__ outs_out, unsigned* __restrict__ flags,
                float* __restrict__ rbuf) {
    const int b   = blockIdx.x & 63;
    const int g   = blockIdx.x >> 6;       // 0..3
    const int tid = threadIdx.x;
    const int ti  = tid & 15;              // n-group (0..15)
    const int tj  = tid >> 4;              // k-group (0..31)
    const int wv  = tid >> 6;              // wave (0..7)
    const int nbase = g * CHUNK;
    const int nloc  = nbase + ti * NPT;    // first owned n (global id)
    const int kbase = tj * KPT;            // first owned k

    __shared__ __align__(16) float r_all[NTOT];
    __shared__ __align__(8)  float part[8 * CHUNK];   // [wave][160]
    __shared__ float win_s[CHUNK * 17];
    __shared__ float wo_s[2 * N_EXC];
    __shared__ float u_s[NIN];
    __shared__ float red0[8], red1[8];
    __shared__ float bo_s[2];

    // ---- named packed-bf16 weight registers: 20 k-slots x 5 n-pairs -------
#define DECLW(K) u32x4 wA##K; unsigned wB##K;
    FOR20(DECLW)
#undef DECLW

#define LOADW(K) {                                                          \
        const int k_ = kbase + (K);                                         \
        const float sg_ = (k_ < N_EXC) ? 1.f : -1.f;                        \
        wA##K = (u32x4){packw2(Wraw, nloc + 0, nloc + 1, k_, sg_),          \
                        packw2(Wraw, nloc + 2, nloc + 3, k_, sg_),          \
                        packw2(Wraw, nloc + 4, nloc + 5, k_, sg_),          \
                        packw2(Wraw, nloc + 6, nloc + 7, k_, sg_)};         \
        wB##K = packw2(Wraw, nloc + 8, nloc + 9, k_, sg_);                  \
    }
    FOR20(LOADW)
#undef LOADW

    // W_in chunk -> LDS (padded stride 17); W_out/b_out -> LDS (saves VGPRs)
    for (int i = tid; i < CHUNK * NIN; i += THREADS) {
        int o = i >> 4, j = i & 15;
        win_s[o * 17 + j] = W_in[(nbase + o) * NIN + j];
    }
    for (int i = tid; i < 2 * N_EXC; i += THREADS) wo_s[i] = W_out[i];
    if (tid < 2) bo_s[tid] = b_out[tid];

    const float* inp_b = inputs    + (size_t)b * TSTEPS * NIN;
    float* rates_b     = rates_out + (size_t)b * TSTEPS * NTOT;
    float* outs_b      = outs_out  + (size_t)b * TSTEPS * 2;
    unsigned* myflag   = flags + (b * NBLKG + g);

    float x = 0.0f;   // owner state for tid < CHUNK
    __syncthreads();  // win_s/wo_s/bo_s ready

    for (int t = 0; t < TSTEPS; ++t) {
        // ---- phase A: rates from current x; publish own chunk -------------
        if (tid < CHUNK) {
            float r = fmaxf(x, 0.0f) + log1pf(expf(-fabsf(x)));
            r_all[nbase + tid] = r;
            rates_b[t * NTOT + nbase + tid] = r;
            float* dst = rbuf + ((size_t)((t & 1) * BATCH + b) * NBLKG + g) * CHUNK + tid;
            __hip_atomic_store(dst, r, __ATOMIC_RELAXED, __HIP_MEMORY_SCOPE_AGENT);
        } else if (tid < CHUNK + NIN) {
            u_s[tid - CHUNK] = inp_b[t * NIN + (tid - CHUNK)];
        }
        __syncthreads();   // drains owners' rbuf stores before flag

        if (tid == 0)
            __hip_atomic_store(myflag, (unsigned)(t + 1), __ATOMIC_RELEASE,
                               __HIP_MEMORY_SCOPE_AGENT);
        if (tid >= 1 && tid < NBLKG) {          // 3 pollers
            int p = tid - 1;
            int gg = p + (p >= g ? 1 : 0);
            unsigned* f = flags + b * NBLKG + gg;
            while (__hip_atomic_load(f, __ATOMIC_ACQUIRE, __HIP_MEMORY_SCOPE_AGENT)
                   < (unsigned)(t + 1)) {
                __builtin_amdgcn_s_sleep(1);
            }
        }
        __syncthreads();

        // ---- phase B: pull remote chunks into r_all ------------------------
        if (tid < 3 * CHUNK) {
            int p = tid / CHUNK;
            int gg = p + (p >= g ? 1 : 0);
            int o = tid - p * CHUNK;
            const float* src = rbuf + ((size_t)((t & 1) * BATCH + b) * NBLKG + gg) * CHUNK + o;
            r_all[gg * CHUNK + o] =
                __hip_atomic_load(src, __ATOMIC_RELAXED, __HIP_MEMORY_SCOPE_AGENT);
        }
        __syncthreads();

        // ---- phase C: packed-bf16 register GEMV + in-wave k-reduction ------
        {
            f32x2 acc0 = {0.f, 0.f}, acc1 = {0.f, 0.f}, acc2 = {0.f, 0.f};
            f32x2 acc3 = {0.f, 0.f}, acc4 = {0.f, 0.f};
#define FMAK(K) { const float rk_ = r_all[kbase + (K)];                     \
                  acc0 += uf2(wA##K.x) * rk_;                               \
                  acc1 += uf2(wA##K.y) * rk_;                               \
                  acc2 += uf2(wA##K.z) * rk_;                               \
                  acc3 += uf2(wA##K.w) * rk_;                               \
                  acc4 += uf2(wB##K)   * rk_; }
            FOR20(FMAK)
#undef FMAK
            // reduce over the 4 tj-groups inside this wave (lane bits 4,5)
#define WRED(S) { S.x += __shfl_xor(S.x, 16); S.x += __shfl_xor(S.x, 32);   \
                  S.y += __shfl_xor(S.y, 16); S.y += __shfl_xor(S.y, 32); }
            WRED(acc0) WRED(acc1) WRED(acc2) WRED(acc3) WRED(acc4)
#undef WRED
            if ((tid & 63) < 16) {             // lane == ti
                float* pp = &part[wv * CHUNK + (tid & 15) * NPT];
                *(f32x2*)(pp + 0) = acc0;
                *(f32x2*)(pp + 2) = acc1;
                *(f32x2*)(pp + 4) = acc2;
                *(f32x2*)(pp + 6) = acc3;
                *(f32x2*)(pp + 8) = acc4;
            }
        }

        // readout partials on g==0 (r_all is complete r_t)
        if (g == 0) {
            float rr = r_all[tid];
            float p0 = rr * wo_s[tid], p1 = rr * wo_s[N_EXC + tid];
#pragma unroll
            for (int off = 32; off; off >>= 1) {
                p0 += __shfl_down(p0, off);
                p1 += __shfl_down(p1, off);
            }
            if ((tid & 63) == 0) { red0[wv] = p0; red1[wv] = p1; }
        }
        __syncthreads();

        // ---- phase D: owner state update ----------------------------------
        if (tid < CHUNK) {
            float rec = 0.0f;
#pragma unroll
            for (int j = 0; j < 8; ++j) rec += part[j * CHUNK + tid];
            float ext = 0.0f;
#pragma unroll
            for (int j = 0; j < NIN; ++j)
                ext = fmaf(win_s[tid * 17 + j], u_s[j], ext);
            unsigned idx = (unsigned)(t * (BATCH * NTOT) + b * NTOT + (nbase + tid));
            float eps = noise_from_bits(jax_bits_partitionable(idx));
            x = (0.5f * x + 0.5f * (rec + ext)) + eps;
        }
        if (g == 0 && tid == 0) {
            float y0 = bo_s[0], y1 = bo_s[1];
#pragma unroll
            for (int k = 0; k < 8; ++k) { y0 += red0[k]; y1 += red1[k]; }
            outs_b[t * 2 + 0] = y0;
            outs_b[t * 2 + 1] = y1;
        }
        __syncthreads();   // protect r_all/part/u_s/red before next iteration
    }
}

// ---------------------------------------------------------------------------
extern "C" void kernel_launch(void* const* d_in, const int* in_sizes, int n_in,
                              void* d_out, int out_size, void* d_ws, size_t ws_size,
                              hipStream_t stream) {
    const float* inputs = (const float*)d_in[0];   // [64,1000,16]
    const float* Wraw   = (const float*)d_in[1];   // [640,640]
    const float* W_in   = (const float*)d_in[2];   // [640,16]
    const float* W_out  = (const float*)d_in[3];   // [2,512]
    const float* b_out  = (const float*)d_in[4];   // [2]

    float* out   = (float*)d_out;
    float* rates = out;                                    // [64,1000,640]
    float* outs  = out + (size_t)BATCH * TSTEPS * NTOT;    // [64,1000,2]

    unsigned* flags = (unsigned*)d_ws;                     // 64*4 u32, zeroed
    float* rbuf = (float*)((char*)d_ws + 4096);            // [2][64][4][160] f32

    hipMemsetAsync(d_ws, 0, 4096, stream);
    eirnn_sync<<<dim3(NBLKG * BATCH), dim3(THREADS), 0, stream>>>(
        inputs, Wraw, W_in, W_out, b_out, rates, outs, flags, rbuf);
}

// Round 11
// 6729.929 us; speedup vs baseline: 2.9001x; 1.7173x over previous
//
#include <hip/hip_runtime.h>

#define N_EXC  512
#define NTOT   640
#define NIN    16
#define BATCH  64
#define TSTEPS 1000
#define CHUNK  160      // units per block
#define NBLKG  4        // blocks per batch sample
#define THREADS 512
#define NPT    10       // n per thread (16 ti-groups * 10 = 160)
#define KPT    20       // k per thread (32 tj-groups * 20 = 640)
#define KREG   12       // k-slots held in registers (60 u32)
#define KLDS   8        // k-slots held in LDS (82 KB -> forces 1 WG/CU)
// ALPHA = 0.5, NOISE_SCALE = 0.01

typedef float    f32x2 __attribute__((ext_vector_type(2)));
typedef unsigned u32x4 __attribute__((ext_vector_type(4)));
typedef unsigned u32x2 __attribute__((ext_vector_type(2)));

// ---------------------------------------------------------------------------
// JAX threefry2x32, key = jax.random.key(42) -> (0, 42); partitionable bits
// ---------------------------------------------------------------------------
__device__ __forceinline__ void threefry_0_42(unsigned x0, unsigned x1,
                                              unsigned& o0, unsigned& o1) {
    const unsigned ks1 = 42u;
    const unsigned ks2 = 0x1BD11BDAu ^ 42u;
    x0 += 0u; x1 += ks1;
#define TF_RND(r) { x0 += x1; x1 = (x1 << (r)) | (x1 >> (32 - (r))); x1 ^= x0; }
    TF_RND(13) TF_RND(15) TF_RND(26) TF_RND(6)
    x0 += ks1; x1 += ks2 + 1u;
    TF_RND(17) TF_RND(29) TF_RND(16) TF_RND(24)
    x0 += ks2; x1 += 0u + 2u;
    TF_RND(13) TF_RND(15) TF_RND(26) TF_RND(6)
    x0 += 0u; x1 += ks1 + 3u;
    TF_RND(17) TF_RND(29) TF_RND(16) TF_RND(24)
    x0 += ks1; x1 += ks2 + 4u;
    TF_RND(13) TF_RND(15) TF_RND(26) TF_RND(6)
    x0 += ks2; x1 += 0u + 5u;
#undef TF_RND
    o0 = x0; o1 = x1;
}

__device__ __forceinline__ unsigned jax_bits_partitionable(unsigned idx) {
    unsigned o0, o1;
    threefry_0_42(0u, idx, o0, o1);
    return o0 ^ o1;
}

// bits -> jax.random.normal sample scaled by NOISE_SCALE*sqrt(ALPHA), f32-exact
__device__ __forceinline__ float noise_from_bits(unsigned bits) {
    float f = __uint_as_float(0x3f800000u | (bits >> 9)) - 1.0f;   // [0,1)
    float u = __fadd_rn(__fmul_rn(f, 2.0f), -0.99999994f);
    u = fmaxf(-0.99999994f, u);
    float w = -log1pf(-__fmul_rn(u, u));
    float p;
    if (w < 5.0f) {
        float ww = w - 2.5f;
        p = 2.81022636e-08f;
        p = fmaf(p, ww, 3.43273939e-07f);
        p = fmaf(p, ww, -3.5233877e-06f);
        p = fmaf(p, ww, -4.39150654e-06f);
        p = fmaf(p, ww, 0.00021858087f);
        p = fmaf(p, ww, -0.00125372503f);
        p = fmaf(p, ww, -0.00417768164f);
        p = fmaf(p, ww, 0.246640727f);
        p = fmaf(p, ww, 1.50140941f);
    } else {
        float ww = sqrtf(w) - 3.0f;
        p = -0.000200214257f;
        p = fmaf(p, ww, 0.000100950558f);
        p = fmaf(p, ww, 0.00134934322f);
        p = fmaf(p, ww, -0.00367342844f);
        p = fmaf(p, ww, 0.00573950773f);
        p = fmaf(p, ww, -0.0076224613f);
        p = fmaf(p, ww, 0.00943887047f);
        p = fmaf(p, ww, 1.00167406f);
        p = fmaf(p, ww, 2.83297682f);
    }
    float z = 1.41421354f * (p * u);
    return (0.01f * 0.70710677f) * z;
}

// round-to-nearest-even bf16 (low 16 bits of result)
__device__ __forceinline__ unsigned rne_bf16(float f) {
    unsigned u = __float_as_uint(f);
    return (u + 0x7FFFu + ((u >> 16) & 1u)) >> 16;
}

// dale-transformed weights for units (n0,n1) at input k, bf16-packed lo|hi<<16
__device__ __forceinline__ unsigned packw2(const float* __restrict__ W,
                                           int n0, int n1, int k, float sg) {
    float lo = fabsf(W[(size_t)n0 * NTOT + k]) * sg; if (n0 == k) lo = 0.f;
    float hi = fabsf(W[(size_t)n1 * NTOT + k]) * sg; if (n1 == k) hi = 0.f;
    return rne_bf16(lo) | (rne_bf16(hi) << 16);
}

// packed u32 -> f32x2 (bf16 lo/hi widened exactly)
__device__ __forceinline__ f32x2 uf2(unsigned u) {
    u32x2 t = {u << 16, u & 0xFFFF0000u};
    return __builtin_bit_cast(f32x2, t);
}

#define FOR12(M) M(0) M(1) M(2) M(3) M(4) M(5) M(6) M(7) M(8) M(9) M(10) M(11)

// ---------------------------------------------------------------------------
// Persistent kernel: 256 blocks = 4 chunk-blocks x 64 batches, 512 threads.
// ALLOCATOR MODEL (r4-r10): VGPR cap = 2048*4 / (waves/CU allowed by LDS);
// LDS 23-34KB -> 2 WGs/CU -> cap 128 -> 200/100-reg panels spilled; attributes
// never moved it. FIX: LDS > 80KB forces 1 WG/CU -> cap 256, and 8 of 20
// k-slots' weights live in that LDS (controlled spill space, own-thread-only
// reads) -> register demand ~95 fits ANY cap. Deadlock-free: 1 WG/CU always.
// ---------------------------------------------------------------------------
__global__ __launch_bounds__(THREADS)
void eirnn_sync(const float* __restrict__ inputs, const float* __restrict__ Wraw,
                const float* __restrict__ W_in, const float* __restrict__ W_out,
                const float* __restrict__ b_out, float* __restrict__ rates_out,
                float* __restrict__ outs_out, unsigned* __restrict__ flags,
                float* __restrict__ rbuf) {
    const int b   = blockIdx.x & 63;
    const int g   = blockIdx.x >> 6;       // 0..3
    const int tid = threadIdx.x;
    const int ti  = tid & 15;              // n-group (0..15)
    const int tj  = tid >> 4;              // k-group (0..31)
    const int wv  = tid >> 6;              // wave (0..7)
    const int nbase = g * CHUNK;
    const int nloc  = nbase + ti * NPT;    // first owned n (global id)
    const int kbase = tj * KPT;            // first owned k

    __shared__ __align__(16) float r_all[NTOT];
    __shared__ __align__(8)  float part[8 * CHUNK];   // [wave][160]
    __shared__ float win_s[CHUNK * 17];
    __shared__ float wo_s[2 * N_EXC];
    __shared__ float u_s[NIN];
    __shared__ float red0[8], red1[8];
    __shared__ float bo_s[2];
    // LDS-resident packed weights for k-slots KREG..KREG+KLDS-1 (own-thread)
    __shared__ u32x4    w4_lds[32 * KLDS * 16];   // 64 KB
    __shared__ unsigned w1_lds[32 * KLDS * 16];   // 16 KB

    // ---- named packed-bf16 weight registers: 12 k-slots x 5 n-pairs -------
#define DECLW(K) u32x4 wA##K; unsigned wB##K;
    FOR12(DECLW)
#undef DECLW

#define LOADW(K) {                                                          \
        const int k_ = kbase + (K);                                         \
        const float sg_ = (k_ < N_EXC) ? 1.f : -1.f;                        \
        wA##K = (u32x4){packw2(Wraw, nloc + 0, nloc + 1, k_, sg_),          \
                        packw2(Wraw, nloc + 2, nloc + 3, k_, sg_),          \
                        packw2(Wraw, nloc + 4, nloc + 5, k_, sg_),          \
                        packw2(Wraw, nloc + 6, nloc + 7, k_, sg_)};         \
        wB##K = packw2(Wraw, nloc + 8, nloc + 9, k_, sg_);                  \
    }
    FOR12(LOADW)
#undef LOADW

    // LDS-resident k-slots (each thread writes/reads only its own entries)
#pragma unroll
    for (int kk = 0; kk < KLDS; ++kk) {
        const int k_ = kbase + KREG + kk;
        const float sg_ = (k_ < N_EXC) ? 1.f : -1.f;
        const int idx = (tj * KLDS + kk) * 16 + ti;
        w4_lds[idx] = (u32x4){packw2(Wraw, nloc + 0, nloc + 1, k_, sg_),
                              packw2(Wraw, nloc + 2, nloc + 3, k_, sg_),
                              packw2(Wraw, nloc + 4, nloc + 5, k_, sg_),
                              packw2(Wraw, nloc + 6, nloc + 7, k_, sg_)};
        w1_lds[idx] = packw2(Wraw, nloc + 8, nloc + 9, k_, sg_);
    }

    // W_in chunk -> LDS (padded stride 17); W_out/b_out -> LDS
    for (int i = tid; i < CHUNK * NIN; i += THREADS) {
        int o = i >> 4, j = i & 15;
        win_s[o * 17 + j] = W_in[(nbase + o) * NIN + j];
    }
    for (int i = tid; i < 2 * N_EXC; i += THREADS) wo_s[i] = W_out[i];
    if (tid < 2) bo_s[tid] = b_out[tid];

    const float* inp_b = inputs    + (size_t)b * TSTEPS * NIN;
    float* rates_b     = rates_out + (size_t)b * TSTEPS * NTOT;
    float* outs_b      = outs_out  + (size_t)b * TSTEPS * 2;
    unsigned* myflag   = flags + (b * NBLKG + g);

    float x = 0.0f;   // owner state for tid < CHUNK
    __syncthreads();  // win_s/wo_s/bo_s ready

    for (int t = 0; t < TSTEPS; ++t) {
        // ---- phase A: rates from current x; publish own chunk -------------
        if (tid < CHUNK) {
            float r = fmaxf(x, 0.0f) + log1pf(expf(-fabsf(x)));
            r_all[nbase + tid] = r;
            rates_b[t * NTOT + nbase + tid] = r;
            float* dst = rbuf + ((size_t)((t & 1) * BATCH + b) * NBLKG + g) * CHUNK + tid;
            __hip_atomic_store(dst, r, __ATOMIC_RELAXED, __HIP_MEMORY_SCOPE_AGENT);
        } else if (tid < CHUNK + NIN) {
            u_s[tid - CHUNK] = inp_b[t * NIN + (tid - CHUNK)];
        }
        __syncthreads();   // drains owners' rbuf stores before flag

        if (tid == 0)
            __hip_atomic_store(myflag, (unsigned)(t + 1), __ATOMIC_RELEASE,
                               __HIP_MEMORY_SCOPE_AGENT);
        if (tid >= 1 && tid < NBLKG) {          // 3 pollers
            int p = tid - 1;
            int gg = p + (p >= g ? 1 : 0);
            unsigned* f = flags + b * NBLKG + gg;
            while (__hip_atomic_load(f, __ATOMIC_ACQUIRE, __HIP_MEMORY_SCOPE_AGENT)
                   < (unsigned)(t + 1)) {
                __builtin_amdgcn_s_sleep(1);
            }
        }
        __syncthreads();

        // ---- phase B: pull remote chunks into r_all ------------------------
        if (tid < 3 * CHUNK) {
            int p = tid / CHUNK;
            int gg = p + (p >= g ? 1 : 0);
            int o = tid - p * CHUNK;
            const float* src = rbuf + ((size_t)((t & 1) * BATCH + b) * NBLKG + gg) * CHUNK + o;
            r_all[gg * CHUNK + o] =
                __hip_atomic_load(src, __ATOMIC_RELAXED, __HIP_MEMORY_SCOPE_AGENT);
        }
        __syncthreads();

        // ---- phase C: hybrid reg/LDS packed-bf16 GEMV + in-wave k-reduce ---
        {
            f32x2 acc0 = {0.f, 0.f}, acc1 = {0.f, 0.f}, acc2 = {0.f, 0.f};
            f32x2 acc3 = {0.f, 0.f}, acc4 = {0.f, 0.f};
            // register k-slots 0..11
#define FMAK(K) { const float rk_ = r_all[kbase + (K)];                     \
                  acc0 += uf2(wA##K.x) * rk_;                               \
                  acc1 += uf2(wA##K.y) * rk_;                               \
                  acc2 += uf2(wA##K.z) * rk_;                               \
                  acc3 += uf2(wA##K.w) * rk_;                               \
                  acc4 += uf2(wB##K)   * rk_; }
            FOR12(FMAK)
#undef FMAK
            // LDS k-slots 12..19
#pragma unroll
            for (int kk = 0; kk < KLDS; ++kk) {
                const float rk_ = r_all[kbase + KREG + kk];
                const int idx = (tj * KLDS + kk) * 16 + ti;
                u32x4 wa = w4_lds[idx];
                unsigned wb = w1_lds[idx];
                acc0 += uf2(wa.x) * rk_;
                acc1 += uf2(wa.y) * rk_;
                acc2 += uf2(wa.z) * rk_;
                acc3 += uf2(wa.w) * rk_;
                acc4 += uf2(wb)   * rk_;
            }
            // reduce over the 4 tj-groups inside this wave (lane bits 4,5)
#define WRED(S) { S.x += __shfl_xor(S.x, 16); S.x += __shfl_xor(S.x, 32);   \
                  S.y += __shfl_xor(S.y, 16); S.y += __shfl_xor(S.y, 32); }
            WRED(acc0) WRED(acc1) WRED(acc2) WRED(acc3) WRED(acc4)
#undef WRED
            if ((tid & 63) < 16) {             // lane == ti
                float* pp = &part[wv * CHUNK + (tid & 15) * NPT];
                *(f32x2*)(pp + 0) = acc0;
                *(f32x2*)(pp + 2) = acc1;
                *(f32x2*)(pp + 4) = acc2;
                *(f32x2*)(pp + 6) = acc3;
                *(f32x2*)(pp + 8) = acc4;
            }
        }

        // readout partials on g==0 (r_all is complete r_t)
        if (g == 0) {
            float rr = r_all[tid];
            float p0 = rr * wo_s[tid], p1 = rr * wo_s[N_EXC + tid];
#pragma unroll
            for (int off = 32; off; off >>= 1) {
                p0 += __shfl_down(p0, off);
                p1 += __shfl_down(p1, off);
            }
            if ((tid & 63) == 0) { red0[wv] = p0; red1[wv] = p1; }
        }
        __syncthreads();

        // ---- phase D: owner state update ----------------------------------
        if (tid < CHUNK) {
            float rec = 0.0f;
#pragma unroll
            for (int j = 0; j < 8; ++j) rec += part[j * CHUNK + tid];
            float ext = 0.0f;
#pragma unroll
            for (int j = 0; j < NIN; ++j)
                ext = fmaf(win_s[tid * 17 + j], u_s[j], ext);
            unsigned idx = (unsigned)(t * (BATCH * NTOT) + b * NTOT + (nbase + tid));
            float eps = noise_from_bits(jax_bits_partitionable(idx));
            x = (0.5f * x + 0.5f * (rec + ext)) + eps;
        }
        if (g == 0 && tid == 0) {
            float y0 = bo_s[0], y1 = bo_s[1];
#pragma unroll
            for (int k = 0; k < 8; ++k) { y0 += red0[k]; y1 += red1[k]; }
            outs_b[t * 2 + 0] = y0;
            outs_b[t * 2 + 1] = y1;
        }
        __syncthreads();   // protect r_all/part/u_s/red before next iteration
    }
}

// ---------------------------------------------------------------------------
extern "C" void kernel_launch(void* const* d_in, const int* in_sizes, int n_in,
                              void* d_out, int out_size, void* d_ws, size_t ws_size,
                              hipStream_t stream) {
    const float* inputs = (const float*)d_in[0];   // [64,1000,16]
    const float* Wraw   = (const float*)d_in[1];   // [640,640]
    const float* W_in   = (const float*)d_in[2];   // [640,16]
    const float* W_out  = (const float*)d_in[3];   // [2,512]
    const float* b_out  = (const float*)d_in[4];   // [2]

    float* out   = (float*)d_out;
    float* rates = out;                                    // [64,1000,640]
    float* outs  = out + (size_t)BATCH * TSTEPS * NTOT;    // [64,1000,2]

    unsigned* flags = (unsigned*)d_ws;                     // 64*4 u32, zeroed
    float* rbuf = (float*)((char*)d_ws + 4096);            // [2][64][4][160] f32

    hipMemsetAsync(d_ws, 0, 4096, stream);
    eirnn_sync<<<dim3(NBLKG * BATCH), dim3(THREADS), 0, stream>>>(
        inputs, Wraw, W_in, W_out, b_out, rates, outs, flags, rbuf);
}

// Round 12
// 6445.914 us; speedup vs baseline: 3.0279x; 1.0441x over previous
//
#include <hip/hip_runtime.h>

#define N_EXC  512
#define NTOT   640
#define NIN    16
#define BATCH  64
#define TSTEPS 1000
#define CHUNK  160      // units per block
#define NBLKG  4        // blocks per batch sample
#define THREADS 512
#define NPT    10       // n per thread (16 ti-groups * 10 = 160)
#define KPT    20       // k per thread (32 tj-groups * 20 = 640)
#define KREG   12       // k-slots held in registers (60 u32)
#define KLDS   8        // k-slots held in LDS (80 KB -> forces 1 WG/CU)
// ALPHA = 0.5, NOISE_SCALE = 0.01

typedef float    f32x2 __attribute__((ext_vector_type(2)));
typedef unsigned u32x4 __attribute__((ext_vector_type(4)));
typedef unsigned u32x2 __attribute__((ext_vector_type(2)));

// ---------------------------------------------------------------------------
// JAX threefry2x32, key = jax.random.key(42) -> (0, 42); partitionable bits
// ---------------------------------------------------------------------------
__device__ __forceinline__ void threefry_0_42(unsigned x0, unsigned x1,
                                              unsigned& o0, unsigned& o1) {
    const unsigned ks1 = 42u;
    const unsigned ks2 = 0x1BD11BDAu ^ 42u;
    x0 += 0u; x1 += ks1;
#define TF_RND(r) { x0 += x1; x1 = (x1 << (r)) | (x1 >> (32 - (r))); x1 ^= x0; }
    TF_RND(13) TF_RND(15) TF_RND(26) TF_RND(6)
    x0 += ks1; x1 += ks2 + 1u;
    TF_RND(17) TF_RND(29) TF_RND(16) TF_RND(24)
    x0 += ks2; x1 += 0u + 2u;
    TF_RND(13) TF_RND(15) TF_RND(26) TF_RND(6)
    x0 += 0u; x1 += ks1 + 3u;
    TF_RND(17) TF_RND(29) TF_RND(16) TF_RND(24)
    x0 += ks1; x1 += ks2 + 4u;
    TF_RND(13) TF_RND(15) TF_RND(26) TF_RND(6)
    x0 += ks2; x1 += 0u + 5u;
#undef TF_RND
    o0 = x0; o1 = x1;
}

__device__ __forceinline__ unsigned jax_bits_partitionable(unsigned idx) {
    unsigned o0, o1;
    threefry_0_42(0u, idx, o0, o1);
    return o0 ^ o1;
}

// bits -> jax.random.normal sample scaled by NOISE_SCALE*sqrt(ALPHA), f32-exact
__device__ __forceinline__ float noise_from_bits(unsigned bits) {
    float f = __uint_as_float(0x3f800000u | (bits >> 9)) - 1.0f;   // [0,1)
    float u = __fadd_rn(__fmul_rn(f, 2.0f), -0.99999994f);
    u = fmaxf(-0.99999994f, u);
    float w = -log1pf(-__fmul_rn(u, u));
    float p;
    if (w < 5.0f) {
        float ww = w - 2.5f;
        p = 2.81022636e-08f;
        p = fmaf(p, ww, 3.43273939e-07f);
        p = fmaf(p, ww, -3.5233877e-06f);
        p = fmaf(p, ww, -4.39150654e-06f);
        p = fmaf(p, ww, 0.00021858087f);
        p = fmaf(p, ww, -0.00125372503f);
        p = fmaf(p, ww, -0.00417768164f);
        p = fmaf(p, ww, 0.246640727f);
        p = fmaf(p, ww, 1.50140941f);
    } else {
        float ww = sqrtf(w) - 3.0f;
        p = -0.000200214257f;
        p = fmaf(p, ww, 0.000100950558f);
        p = fmaf(p, ww, 0.00134934322f);
        p = fmaf(p, ww, -0.00367342844f);
        p = fmaf(p, ww, 0.00573950773f);
        p = fmaf(p, ww, -0.0076224613f);
        p = fmaf(p, ww, 0.00943887047f);
        p = fmaf(p, ww, 1.00167406f);
        p = fmaf(p, ww, 2.83297682f);
    }
    float z = 1.41421354f * (p * u);
    return (0.01f * 0.70710677f) * z;
}

// round-to-nearest-even bf16 (low 16 bits of result)
__device__ __forceinline__ unsigned rne_bf16(float f) {
    unsigned u = __float_as_uint(f);
    return (u + 0x7FFFu + ((u >> 16) & 1u)) >> 16;
}

// dale-transformed weights for units (n0,n1) at input k, bf16-packed lo|hi<<16
__device__ __forceinline__ unsigned packw2(const float* __restrict__ W,
                                           int n0, int n1, int k, float sg) {
    float lo = fabsf(W[(size_t)n0 * NTOT + k]) * sg; if (n0 == k) lo = 0.f;
    float hi = fabsf(W[(size_t)n1 * NTOT + k]) * sg; if (n1 == k) hi = 0.f;
    return rne_bf16(lo) | (rne_bf16(hi) << 16);
}

// packed u32 -> f32x2 (bf16 lo/hi widened exactly)
__device__ __forceinline__ f32x2 uf2(unsigned u) {
    u32x2 t = {u << 16, u & 0xFFFF0000u};
    return __builtin_bit_cast(f32x2, t);
}

#define FOR12(M) M(0) M(1) M(2) M(3) M(4) M(5) M(6) M(7) M(8) M(9) M(10) M(11)

// ---------------------------------------------------------------------------
// Persistent kernel: 256 blocks = 4 chunk-blocks x 64 batches, 512 threads.
// r11-proven: LDS>80KB -> 1 WG/CU -> 256-VGPR cap; 60 reg-u32 + 80KB LDS
// weights, no spill (VGPR=116). r12 changes:
//  (1) lane-major LDS weight layout (w[kk*512+tid]) — wave reads 64x16B
//      contiguous, kills the 8-way bank conflict (3.28e7 cycles in r11).
//  (2) RELAXED agent polling + single ACQUIRE after detection — r11's
//      acquire-per-poll emitted buffer_inv sc1 (full L1/L2 invalidate) every
//      iteration, pushing the per-step chain to HBM latency (FETCH 99MB).
// ---------------------------------------------------------------------------
__global__ __launch_bounds__(THREADS)
void eirnn_sync(const float* __restrict__ inputs, const float* __restrict__ Wraw,
                const float* __restrict__ W_in, const float* __restrict__ W_out,
                const float* __restrict__ b_out, float* __restrict__ rates_out,
                float* __restrict__ outs_out, unsigned* __restrict__ flags,
                float* __restrict__ rbuf) {
    const int b   = blockIdx.x & 63;
    const int g   = blockIdx.x >> 6;       // 0..3
    const int tid = threadIdx.x;
    const int ti  = tid & 15;              // n-group (0..15)
    const int tj  = tid >> 4;              // k-group (0..31)
    const int wv  = tid >> 6;              // wave (0..7)
    const int nbase = g * CHUNK;
    const int nloc  = nbase + ti * NPT;    // first owned n (global id)
    const int kbase = tj * KPT;            // first owned k

    __shared__ __align__(16) float r_all[NTOT];
    __shared__ __align__(8)  float part[8 * CHUNK];   // [wave][160]
    __shared__ float win_s[CHUNK * 17];
    __shared__ float wo_s[2 * N_EXC];
    __shared__ float u_s[NIN];
    __shared__ float red0[8], red1[8];
    __shared__ float bo_s[2];
    // LDS-resident packed weights, LANE-MAJOR: [kk][tid] -> wave-contiguous
    __shared__ u32x4    w4_lds[KLDS * THREADS];   // 64 KB
    __shared__ unsigned w1_lds[KLDS * THREADS];   // 16 KB

    // ---- named packed-bf16 weight registers: 12 k-slots x 5 n-pairs -------
#define DECLW(K) u32x4 wA##K; unsigned wB##K;
    FOR12(DECLW)
#undef DECLW

#define LOADW(K) {                                                          \
        const int k_ = kbase + (K);                                         \
        const float sg_ = (k_ < N_EXC) ? 1.f : -1.f;                        \
        wA##K = (u32x4){packw2(Wraw, nloc + 0, nloc + 1, k_, sg_),          \
                        packw2(Wraw, nloc + 2, nloc + 3, k_, sg_),          \
                        packw2(Wraw, nloc + 4, nloc + 5, k_, sg_),          \
                        packw2(Wraw, nloc + 6, nloc + 7, k_, sg_)};         \
        wB##K = packw2(Wraw, nloc + 8, nloc + 9, k_, sg_);                  \
    }
    FOR12(LOADW)
#undef LOADW

    // LDS-resident k-slots (own-thread entries, lane-major layout)
#pragma unroll
    for (int kk = 0; kk < KLDS; ++kk) {
        const int k_ = kbase + KREG + kk;
        const float sg_ = (k_ < N_EXC) ? 1.f : -1.f;
        w4_lds[kk * THREADS + tid] =
            (u32x4){packw2(Wraw, nloc + 0, nloc + 1, k_, sg_),
                    packw2(Wraw, nloc + 2, nloc + 3, k_, sg_),
                    packw2(Wraw, nloc + 4, nloc + 5, k_, sg_),
                    packw2(Wraw, nloc + 6, nloc + 7, k_, sg_)};
        w1_lds[kk * THREADS + tid] = packw2(Wraw, nloc + 8, nloc + 9, k_, sg_);
    }

    // W_in chunk -> LDS (padded stride 17); W_out/b_out -> LDS
    for (int i = tid; i < CHUNK * NIN; i += THREADS) {
        int o = i >> 4, j = i & 15;
        win_s[o * 17 + j] = W_in[(nbase + o) * NIN + j];
    }
    for (int i = tid; i < 2 * N_EXC; i += THREADS) wo_s[i] = W_out[i];
    if (tid < 2) bo_s[tid] = b_out[tid];

    const float* inp_b = inputs    + (size_t)b * TSTEPS * NIN;
    float* rates_b     = rates_out + (size_t)b * TSTEPS * NTOT;
    float* outs_b      = outs_out  + (size_t)b * TSTEPS * 2;
    unsigned* myflag   = flags + (b * NBLKG + g);

    float x = 0.0f;   // owner state for tid < CHUNK
    __syncthreads();  // LDS weights/win_s/wo_s/bo_s ready

    for (int t = 0; t < TSTEPS; ++t) {
        // ---- phase A: rates from current x; publish own chunk -------------
        if (tid < CHUNK) {
            float r = fmaxf(x, 0.0f) + log1pf(expf(-fabsf(x)));
            r_all[nbase + tid] = r;
            rates_b[t * NTOT + nbase + tid] = r;
            float* dst = rbuf + ((size_t)((t & 1) * BATCH + b) * NBLKG + g) * CHUNK + tid;
            __hip_atomic_store(dst, r, __ATOMIC_RELAXED, __HIP_MEMORY_SCOPE_AGENT);
        } else if (tid < CHUNK + NIN) {
            u_s[tid - CHUNK] = inp_b[t * NIN + (tid - CHUNK)];
        }
        __syncthreads();   // drains owners' rbuf stores before flag

        if (tid == 0)
            __hip_atomic_store(myflag, (unsigned)(t + 1), __ATOMIC_RELEASE,
                               __HIP_MEMORY_SCOPE_AGENT);
        if (tid >= 1 && tid < NBLKG) {          // 3 pollers
            int p = tid - 1;
            int gg = p + (p >= g ? 1 : 0);
            unsigned* f = flags + b * NBLKG + gg;
            // RELAXED agent polls read the coherence point without the
            // per-iteration L1/L2 invalidate an ACQUIRE load emits.
            while (__hip_atomic_load(f, __ATOMIC_RELAXED, __HIP_MEMORY_SCOPE_AGENT)
                   < (unsigned)(t + 1)) {
                __builtin_amdgcn_s_sleep(1);
            }
            // one acquire to order subsequent reads (single invalidate/step)
            (void)__hip_atomic_load(f, __ATOMIC_ACQUIRE, __HIP_MEMORY_SCOPE_AGENT);
        }
        __syncthreads();

        // ---- phase B: pull remote chunks into r_all ------------------------
        if (tid < 3 * CHUNK) {
            int p = tid / CHUNK;
            int gg = p + (p >= g ? 1 : 0);
            int o = tid - p * CHUNK;
            const float* src = rbuf + ((size_t)((t & 1) * BATCH + b) * NBLKG + gg) * CHUNK + o;
            r_all[gg * CHUNK + o] =
                __hip_atomic_load(src, __ATOMIC_RELAXED, __HIP_MEMORY_SCOPE_AGENT);
        }
        __syncthreads();

        // ---- phase C: hybrid reg/LDS packed-bf16 GEMV + in-wave k-reduce ---
        {
            f32x2 acc0 = {0.f, 0.f}, acc1 = {0.f, 0.f}, acc2 = {0.f, 0.f};
            f32x2 acc3 = {0.f, 0.f}, acc4 = {0.f, 0.f};
            // register k-slots 0..11
#define FMAK(K) { const float rk_ = r_all[kbase + (K)];                     \
                  acc0 += uf2(wA##K.x) * rk_;                               \
                  acc1 += uf2(wA##K.y) * rk_;                               \
                  acc2 += uf2(wA##K.z) * rk_;                               \
                  acc3 += uf2(wA##K.w) * rk_;                               \
                  acc4 += uf2(wB##K)   * rk_; }
            FOR12(FMAK)
#undef FMAK
            // LDS k-slots 12..19 (lane-major, conflict-free)
#pragma unroll
            for (int kk = 0; kk < KLDS; ++kk) {
                const float rk_ = r_all[kbase + KREG + kk];
                u32x4 wa = w4_lds[kk * THREADS + tid];
                unsigned wb = w1_lds[kk * THREADS + tid];
                acc0 += uf2(wa.x) * rk_;
                acc1 += uf2(wa.y) * rk_;
                acc2 += uf2(wa.z) * rk_;
                acc3 += uf2(wa.w) * rk_;
                acc4 += uf2(wb)   * rk_;
            }
            // reduce over the 4 tj-groups inside this wave (lane bits 4,5)
#define WRED(S) { S.x += __shfl_xor(S.x, 16); S.x += __shfl_xor(S.x, 32);   \
                  S.y += __shfl_xor(S.y, 16); S.y += __shfl_xor(S.y, 32); }
            WRED(acc0) WRED(acc1) WRED(acc2) WRED(acc3) WRED(acc4)
#undef WRED
            if ((tid & 63) < 16) {             // lane == ti
                float* pp = &part[wv * CHUNK + (tid & 15) * NPT];
                *(f32x2*)(pp + 0) = acc0;
                *(f32x2*)(pp + 2) = acc1;
                *(f32x2*)(pp + 4) = acc2;
                *(f32x2*)(pp + 6) = acc3;
                *(f32x2*)(pp + 8) = acc4;
            }
        }

        // readout partials on g==0 (r_all is complete r_t)
        if (g == 0) {
            float rr = r_all[tid];
            float p0 = rr * wo_s[tid], p1 = rr * wo_s[N_EXC + tid];
#pragma unroll
            for (int off = 32; off; off >>= 1) {
                p0 += __shfl_down(p0, off);
                p1 += __shfl_down(p1, off);
            }
            if ((tid & 63) == 0) { red0[wv] = p0; red1[wv] = p1; }
        }
        __syncthreads();

        // ---- phase D: owner state update ----------------------------------
        if (tid < CHUNK) {
            float rec = 0.0f;
#pragma unroll
            for (int j = 0; j < 8; ++j) rec += part[j * CHUNK + tid];
            float ext = 0.0f;
#pragma unroll
            for (int j = 0; j < NIN; ++j)
                ext = fmaf(win_s[tid * 17 + j], u_s[j], ext);
            unsigned idx = (unsigned)(t * (BATCH * NTOT) + b * NTOT + (nbase + tid));
            float eps = noise_from_bits(jax_bits_partitionable(idx));
            x = (0.5f * x + 0.5f * (rec + ext)) + eps;
        }
        if (g == 0 && tid == 0) {
            float y0 = bo_s[0], y1 = bo_s[1];
#pragma unroll
            for (int k = 0; k < 8; ++k) { y0 += red0[k]; y1 += red1[k]; }
            outs_b[t * 2 + 0] = y0;
            outs_b[t * 2 + 1] = y1;
        }
        __syncthreads();   // protect r_all/part/u_s/red before next iteration
    }
}

// ---------------------------------------------------------------------------
extern "C" void kernel_launch(void* const* d_in, const int* in_sizes, int n_in,
                              void* d_out, int out_size, void* d_ws, size_t ws_size,
                              hipStream_t stream) {
    const float* inputs = (const float*)d_in[0];   // [64,1000,16]
    const float* Wraw   = (const float*)d_in[1];   // [640,640]
    const float* W_in   = (const float*)d_in[2];   // [640,16]
    const float* W_out  = (const float*)d_in[3];   // [2,512]
    const float* b_out  = (const float*)d_in[4];   // [2]

    float* out   = (float*)d_out;
    float* rates = out;                                    // [64,1000,640]
    float* outs  = out + (size_t)BATCH * TSTEPS * NTOT;    // [64,1000,2]

    unsigned* flags = (unsigned*)d_ws;                     // 64*4 u32, zeroed
    float* rbuf = (float*)((char*)d_ws + 4096);            // [2][64][4][160] f32

    hipMemsetAsync(d_ws, 0, 4096, stream);
    eirnn_sync<<<dim3(NBLKG * BATCH), dim3(THREADS), 0, stream>>>(
        inputs, Wraw, W_in, W_out, b_out, rates, outs, flags, rbuf);
}

// Round 13
// 3045.934 us; speedup vs baseline: 6.4077x; 2.1162x over previous
//
#include <hip/hip_runtime.h>

#define N_EXC  512
#define NTOT   640
#define NIN    16
#define BATCH  64
#define TSTEPS 1000
#define CHUNK  160      // units per block
#define NBLKG  4        // blocks per batch sample
#define THREADS 512
#define NPT    10       // n per thread (16 ti-groups * 10 = 160)
#define KPT    20       // k per thread (32 tj-groups * 20 = 640)
#define KREG   12       // k-slots held in registers (60 u32)
#define KLDS   8        // k-slots held in LDS (80 KB -> forces 1 WG/CU)
#define RBUF_BYTES (2 * BATCH * NBLKG * CHUNK * 4)   // 327680
// ALPHA = 0.5, NOISE_SCALE = 0.01

typedef float    f32x2 __attribute__((ext_vector_type(2)));
typedef unsigned u32x4 __attribute__((ext_vector_type(4)));
typedef unsigned u32x2 __attribute__((ext_vector_type(2)));

// ---------------------------------------------------------------------------
// JAX threefry2x32, key = jax.random.key(42) -> (0, 42); partitionable bits
// ---------------------------------------------------------------------------
__device__ __forceinline__ void threefry_0_42(unsigned x0, unsigned x1,
                                              unsigned& o0, unsigned& o1) {
    const unsigned ks1 = 42u;
    const unsigned ks2 = 0x1BD11BDAu ^ 42u;
    x0 += 0u; x1 += ks1;
#define TF_RND(r) { x0 += x1; x1 = (x1 << (r)) | (x1 >> (32 - (r))); x1 ^= x0; }
    TF_RND(13) TF_RND(15) TF_RND(26) TF_RND(6)
    x0 += ks1; x1 += ks2 + 1u;
    TF_RND(17) TF_RND(29) TF_RND(16) TF_RND(24)
    x0 += ks2; x1 += 0u + 2u;
    TF_RND(13) TF_RND(15) TF_RND(26) TF_RND(6)
    x0 += 0u; x1 += ks1 + 3u;
    TF_RND(17) TF_RND(29) TF_RND(16) TF_RND(24)
    x0 += ks1; x1 += ks2 + 4u;
    TF_RND(13) TF_RND(15) TF_RND(26) TF_RND(6)
    x0 += ks2; x1 += 0u + 5u;
#undef TF_RND
    o0 = x0; o1 = x1;
}

__device__ __forceinline__ unsigned jax_bits_partitionable(unsigned idx) {
    unsigned o0, o1;
    threefry_0_42(0u, idx, o0, o1);
    return o0 ^ o1;
}

// bits -> jax.random.normal sample scaled by NOISE_SCALE*sqrt(ALPHA), f32-exact
__device__ __forceinline__ float noise_from_bits(unsigned bits) {
    float f = __uint_as_float(0x3f800000u | (bits >> 9)) - 1.0f;   // [0,1)
    float u = __fadd_rn(__fmul_rn(f, 2.0f), -0.99999994f);
    u = fmaxf(-0.99999994f, u);
    float w = -log1pf(-__fmul_rn(u, u));
    float p;
    if (w < 5.0f) {
        float ww = w - 2.5f;
        p = 2.81022636e-08f;
        p = fmaf(p, ww, 3.43273939e-07f);
        p = fmaf(p, ww, -3.5233877e-06f);
        p = fmaf(p, ww, -4.39150654e-06f);
        p = fmaf(p, ww, 0.00021858087f);
        p = fmaf(p, ww, -0.00125372503f);
        p = fmaf(p, ww, -0.00417768164f);
        p = fmaf(p, ww, 0.246640727f);
        p = fmaf(p, ww, 1.50140941f);
    } else {
        float ww = sqrtf(w) - 3.0f;
        p = -0.000200214257f;
        p = fmaf(p, ww, 0.000100950558f);
        p = fmaf(p, ww, 0.00134934322f);
        p = fmaf(p, ww, -0.00367342844f);
        p = fmaf(p, ww, 0.00573950773f);
        p = fmaf(p, ww, -0.0076224613f);
        p = fmaf(p, ww, 0.00943887047f);
        p = fmaf(p, ww, 1.00167406f);
        p = fmaf(p, ww, 2.83297682f);
    }
    float z = 1.41421354f * (p * u);
    return (0.01f * 0.70710677f) * z;
}

// round-to-nearest-even bf16 (low 16 bits of result)
__device__ __forceinline__ unsigned rne_bf16(float f) {
    unsigned u = __float_as_uint(f);
    return (u + 0x7FFFu + ((u >> 16) & 1u)) >> 16;
}

// dale-transformed weights for units (n0,n1) at input k, bf16-packed lo|hi<<16
__device__ __forceinline__ unsigned packw2(const float* __restrict__ W,
                                           int n0, int n1, int k, float sg) {
    float lo = fabsf(W[(size_t)n0 * NTOT + k]) * sg; if (n0 == k) lo = 0.f;
    float hi = fabsf(W[(size_t)n1 * NTOT + k]) * sg; if (n1 == k) hi = 0.f;
    return rne_bf16(lo) | (rne_bf16(hi) << 16);
}

// packed u32 -> f32x2 (bf16 lo/hi widened exactly)
__device__ __forceinline__ f32x2 uf2(unsigned u) {
    u32x2 t = {u << 16, u & 0xFFFF0000u};
    return __builtin_bit_cast(f32x2, t);
}

#define FOR12(M) M(0) M(1) M(2) M(3) M(4) M(5) M(6) M(7) M(8) M(9) M(10) M(11)

// ---------------------------------------------------------------------------
// Persistent kernel: 256 blocks = 4 chunk-blocks x 64 batches, 512 threads.
// r11/r12-proven: LDS>80KB -> 1 WG/CU -> no spill (VGPR=116); lane-major LDS
// weights (conflict-free). r13: SELF-FLAGGING DATA sync.
//   - published rate word carries a 2-bit step tag (t&3) in low mantissa bits;
//     rates>0 so (tag match && positive-normal) <=> this step's data. No flag
//     array, no acquire invalidates, no separate phase-B read pass.
//   - 480 threads poll their own remote word in parallel (relaxed agent loads).
//   - r_all/u_s parity-double-buffered -> 2 barriers/step (was 5).
//   - rbuf sentinel-memset (0xAA, tag=2, negative) each call, in-graph.
// ---------------------------------------------------------------------------
__global__ __launch_bounds__(THREADS)
void eirnn_sync(const float* __restrict__ inputs, const float* __restrict__ Wraw,
                const float* __restrict__ W_in, const float* __restrict__ W_out,
                const float* __restrict__ b_out, float* __restrict__ rates_out,
                float* __restrict__ outs_out, unsigned* __restrict__ rbuf) {
    const int b   = blockIdx.x & 63;
    const int g   = blockIdx.x >> 6;       // 0..3
    const int tid = threadIdx.x;
    const int ti  = tid & 15;              // n-group (0..15)
    const int tj  = tid >> 4;              // k-group (0..31)
    const int wv  = tid >> 6;              // wave (0..7)
    const int nbase = g * CHUNK;
    const int nloc  = nbase + ti * NPT;    // first owned n (global id)
    const int kbase = tj * KPT;            // first owned k

    __shared__ __align__(16) float r_all[2][NTOT];
    __shared__ __align__(8)  float part[8 * CHUNK];   // [wave][160]
    __shared__ float win_s[CHUNK * 17];
    __shared__ float wo_s[2 * N_EXC];
    __shared__ float u_s[2][NIN];
    __shared__ float red0[8], red1[8];
    __shared__ float bo_s[2];
    // LDS-resident packed weights, LANE-MAJOR: [kk][tid] -> wave-contiguous
    __shared__ u32x4    w4_lds[KLDS * THREADS];   // 64 KB
    __shared__ unsigned w1_lds[KLDS * THREADS];   // 16 KB

    // ---- named packed-bf16 weight registers: 12 k-slots x 5 n-pairs -------
#define DECLW(K) u32x4 wA##K; unsigned wB##K;
    FOR12(DECLW)
#undef DECLW

#define LOADW(K) {                                                          \
        const int k_ = kbase + (K);                                         \
        const float sg_ = (k_ < N_EXC) ? 1.f : -1.f;                        \
        wA##K = (u32x4){packw2(Wraw, nloc + 0, nloc + 1, k_, sg_),          \
                        packw2(Wraw, nloc + 2, nloc + 3, k_, sg_),          \
                        packw2(Wraw, nloc + 4, nloc + 5, k_, sg_),          \
                        packw2(Wraw, nloc + 6, nloc + 7, k_, sg_)};         \
        wB##K = packw2(Wraw, nloc + 8, nloc + 9, k_, sg_);                  \
    }
    FOR12(LOADW)
#undef LOADW

    // LDS-resident k-slots (own-thread entries, lane-major layout)
#pragma unroll
    for (int kk = 0; kk < KLDS; ++kk) {
        const int k_ = kbase + KREG + kk;
        const float sg_ = (k_ < N_EXC) ? 1.f : -1.f;
        w4_lds[kk * THREADS + tid] =
            (u32x4){packw2(Wraw, nloc + 0, nloc + 1, k_, sg_),
                    packw2(Wraw, nloc + 2, nloc + 3, k_, sg_),
                    packw2(Wraw, nloc + 4, nloc + 5, k_, sg_),
                    packw2(Wraw, nloc + 6, nloc + 7, k_, sg_)};
        w1_lds[kk * THREADS + tid] = packw2(Wraw, nloc + 8, nloc + 9, k_, sg_);
    }

    // W_in chunk -> LDS (padded stride 17); W_out/b_out -> LDS
    for (int i = tid; i < CHUNK * NIN; i += THREADS) {
        int o = i >> 4, j = i & 15;
        win_s[o * 17 + j] = W_in[(nbase + o) * NIN + j];
    }
    for (int i = tid; i < 2 * N_EXC; i += THREADS) wo_s[i] = W_out[i];
    if (tid < 2) bo_s[tid] = b_out[tid];

    const float* inp_b = inputs    + (size_t)b * TSTEPS * NIN;
    float* rates_b     = rates_out + (size_t)b * TSTEPS * NTOT;
    float* outs_b      = outs_out  + (size_t)b * TSTEPS * 2;

    // poller role: threads [32, 512) each own one remote word
    const int pidx = tid - 32;             // 0..479 when tid>=32
    const int pp   = pidx / CHUNK;         // 0..2
    const int pgg  = pp + (pp >= g ? 1 : 0);
    const int po   = pidx - pp * CHUNK;

    float x = 0.0f;   // owner state for tid < CHUNK
    __syncthreads();  // LDS weights/win_s/wo_s/bo_s ready

    for (int t = 0; t < TSTEPS; ++t) {
        const int buf = t & 1;
        const unsigned tagv = (unsigned)(t & 3);
        unsigned* rb_base = rbuf + (size_t)(buf * BATCH + b) * (NBLKG * CHUNK);

        // ---- phase A: owners publish tagged rate; pollers pull remote ------
        if (tid < CHUNK) {
            float r = fmaxf(x, 0.0f) + log1pf(expf(-fabsf(x)));
            unsigned rbits = (__float_as_uint(r) & ~3u) | tagv;
            r_all[buf][nbase + tid] = __uint_as_float(rbits);  // tagged (uniform)
            rates_b[t * NTOT + nbase + tid] = r;               // exact output
            __hip_atomic_store(rb_base + g * CHUNK + tid, rbits,
                               __ATOMIC_RELAXED, __HIP_MEMORY_SCOPE_AGENT);
        }
        if (tid >= THREADS - NIN) {        // 16 u-loaders (also pollers)
            u_s[buf][tid - (THREADS - NIN)] =
                inp_b[t * NIN + (tid - (THREADS - NIN))];
        }
        if (tid >= 32) {                   // 480 pollers: data IS the flag
            const unsigned* src = rb_base + pgg * CHUNK + po;
            unsigned w;
            do {
                w = __hip_atomic_load(src, __ATOMIC_RELAXED,
                                      __HIP_MEMORY_SCOPE_AGENT);
            } while (((w & 3u) != tagv) || ((int)w <= 0x00800000));
            r_all[buf][pgg * CHUNK + po] = __uint_as_float(w);
        }
        __syncthreads();   // r_all[buf] complete

        // ---- phase C: hybrid reg/LDS packed-bf16 GEMV + in-wave k-reduce ---
        {
            const float* ra = r_all[buf];
            f32x2 acc0 = {0.f, 0.f}, acc1 = {0.f, 0.f}, acc2 = {0.f, 0.f};
            f32x2 acc3 = {0.f, 0.f}, acc4 = {0.f, 0.f};
#define FMAK(K) { const float rk_ = ra[kbase + (K)];                        \
                  acc0 += uf2(wA##K.x) * rk_;                               \
                  acc1 += uf2(wA##K.y) * rk_;                               \
                  acc2 += uf2(wA##K.z) * rk_;                               \
                  acc3 += uf2(wA##K.w) * rk_;                               \
                  acc4 += uf2(wB##K)   * rk_; }
            FOR12(FMAK)
#undef FMAK
#pragma unroll
            for (int kk = 0; kk < KLDS; ++kk) {
                const float rk_ = ra[kbase + KREG + kk];
                u32x4 wa = w4_lds[kk * THREADS + tid];
                unsigned wb = w1_lds[kk * THREADS + tid];
                acc0 += uf2(wa.x) * rk_;
                acc1 += uf2(wa.y) * rk_;
                acc2 += uf2(wa.z) * rk_;
                acc3 += uf2(wa.w) * rk_;
                acc4 += uf2(wb)   * rk_;
            }
#define WRED(S) { S.x += __shfl_xor(S.x, 16); S.x += __shfl_xor(S.x, 32);   \
                  S.y += __shfl_xor(S.y, 16); S.y += __shfl_xor(S.y, 32); }
            WRED(acc0) WRED(acc1) WRED(acc2) WRED(acc3) WRED(acc4)
#undef WRED
            if ((tid & 63) < 16) {             // lane == ti
                float* pq = &part[wv * CHUNK + (tid & 15) * NPT];
                *(f32x2*)(pq + 0) = acc0;
                *(f32x2*)(pq + 2) = acc1;
                *(f32x2*)(pq + 4) = acc2;
                *(f32x2*)(pq + 6) = acc3;
                *(f32x2*)(pq + 8) = acc4;
            }
            // readout partials on g==0 (r_all[buf] is complete r_t)
            if (g == 0) {
                float rr = r_all[buf][tid];
                float p0 = rr * wo_s[tid], p1 = rr * wo_s[N_EXC + tid];
#pragma unroll
                for (int off = 32; off; off >>= 1) {
                    p0 += __shfl_down(p0, off);
                    p1 += __shfl_down(p1, off);
                }
                if ((tid & 63) == 0) { red0[wv] = p0; red1[wv] = p1; }
            }
        }
        __syncthreads();   // part/red ready; r_all[buf] consumption done

        // ---- phase D: owner state update (no trailing barrier) -------------
        if (tid < CHUNK) {
            float rec = 0.0f;
#pragma unroll
            for (int j = 0; j < 8; ++j) rec += part[j * CHUNK + tid];
            float ext = 0.0f;
#pragma unroll
            for (int j = 0; j < NIN; ++j)
                ext = fmaf(win_s[tid * 17 + j], u_s[buf][j], ext);
            unsigned idx = (unsigned)(t * (BATCH * NTOT) + b * NTOT + (nbase + tid));
            float eps = noise_from_bits(jax_bits_partitionable(idx));
            x = (0.5f * x + 0.5f * (rec + ext)) + eps;
        }
        if (g == 0 && tid == 0) {
            float y0 = bo_s[0], y1 = bo_s[1];
#pragma unroll
            for (int k = 0; k < 8; ++k) { y0 += red0[k]; y1 += red1[k]; }
            outs_b[t * 2 + 0] = y0;
            outs_b[t * 2 + 1] = y1;
        }
        // next iteration's writes are fenced by next barriers (parity buffers)
    }
}

// ---------------------------------------------------------------------------
extern "C" void kernel_launch(void* const* d_in, const int* in_sizes, int n_in,
                              void* d_out, int out_size, void* d_ws, size_t ws_size,
                              hipStream_t stream) {
    const float* inputs = (const float*)d_in[0];   // [64,1000,16]
    const float* Wraw   = (const float*)d_in[1];   // [640,640]
    const float* W_in   = (const float*)d_in[2];   // [640,16]
    const float* W_out  = (const float*)d_in[3];   // [2,512]
    const float* b_out  = (const float*)d_in[4];   // [2]

    float* out   = (float*)d_out;
    float* rates = out;                                    // [64,1000,640]
    float* outs  = out + (size_t)BATCH * TSTEPS * NTOT;    // [64,1000,2]

    unsigned* rbuf = (unsigned*)d_ws;   // [2][64][4][160] u32 (tagged rates)

    // sentinel-fill each call (0xAAAAAAAA: negative & tag=2 -> rejected at
    // t=0 (tag 0) and t=1 (tag 1); in-graph so every replay is identical)
    hipMemsetAsync(d_ws, 0xAA, RBUF_BYTES, stream);
    eirnn_sync<<<dim3(NBLKG * BATCH), dim3(THREADS), 0, stream>>>(
        inputs, Wraw, W_in, W_out, b_out, rates, outs, rbuf);
}